// Round 2
// baseline (1195.877 us; speedup 1.0000x reference)
//
#include <hip/hip_runtime.h>
#include <hip/hip_bf16.h>

// Problem constants (from reference): N=1e6 nodes, V=6e5 var nodes, H=128.
constexpr int H = 128;
constexpr int V = 600000;
constexpr int NTOT = 1000000;

// Precompute u[h] = sum_k W_llr[k] * W_gate[(H+k)*H + h]
//            c[h] = sum_k b_llr[k] * W_gate[(H+k)*H + h] + b_gate[h]
// so logits[i][h] = var_f[i] . W1[:,h] + llr_i * u[h] + c[h]
__global__ void precompute_uc_kernel(const float* __restrict__ W_llr,
                                     const float* __restrict__ b_llr,
                                     const float* __restrict__ W_gate,
                                     const float* __restrict__ b_gate,
                                     float* __restrict__ uc) {
    int h = threadIdx.x;  // 128 threads
    float u = 0.0f, c = 0.0f;
    for (int k = 0; k < H; ++k) {
        float w2 = W_gate[(size_t)(H + k) * H + h];
        u += W_llr[k] * w2;
        c += b_llr[k] * w2;
    }
    uc[h] = u;
    uc[H + h] = c + b_gate[h];
}

// One thread = one row, ENTIRE row held in 32 float4 VGPRs (read once).
// 16 column-chunks of 8 accumulators; k fully unrolled inside the rolled
// chunk loop so every register index is compile-time static. W1 rows are
// wave-uniform -> s_load (scalar pipe), FMAs are v_fmac v,s,v.
// Copy-role blocks (b%5==4) interleave with compute blocks so their pure-BW
// traffic overlaps the compute phase.
__global__ __launch_bounds__(256) void fused_residual_llr_kernel(
    const float* __restrict__ nf,      // node_features [N][H]
    const float* __restrict__ llr,     // original_llr [V]
    const float* __restrict__ W_llr,   // [H]
    const float* __restrict__ b_llr,   // [H]
    const float* __restrict__ W_gate,  // [2H][H]
    const float* __restrict__ uc,      // [2H]: u then c
    float* __restrict__ out) {         // [N][H]
    int b = blockIdx.x;

    if (b % 5 == 4) {
        // ---- copy region: rows V..N, coalesced float4 grid-stride ----
        size_t base = (size_t)V * H;
        size_t n4 = ((size_t)(NTOT - V) * H) / 4;  // 12.8M float4
        const float4* src = reinterpret_cast<const float4*>(nf + base);
        float4* dst = reinterpret_cast<float4*>(out + base);
        size_t i = (size_t)(b / 5) * 256 + threadIdx.x;
        size_t stride = (size_t)(gridDim.x / 5) * 256;
        for (; i < n4; i += stride) dst[i] = src[i];
        return;
    }

    // ---- compute region: one row per thread ----
    int cb = b - b / 5;  // compute-block index (b%5 != 4)
    int r = cb * 256 + (int)threadIdx.x;
    if (r >= V) return;

    const float4* frow = reinterpret_cast<const float4*>(nf + (size_t)r * H);
    float4* orow = reinterpret_cast<float4*>(out + (size_t)r * H);

    // Load full row into registers (read ONCE from HBM).
    float4 row[32];
#pragma unroll
    for (int j = 0; j < 32; ++j) row[j] = frow[j];
    float l = llr[r];

#pragma unroll 1
    for (int cc = 0; cc < 16; ++cc) {  // 8 output cols per chunk
        float acc[8];
#pragma unroll
        for (int c = 0; c < 8; ++c)
            acc[c] = fmaf(l, uc[cc * 8 + c], uc[H + cc * 8 + c]);

        // k fully unrolled: 32 float4 groups x 4 components
#pragma unroll
        for (int kg = 0; kg < 32; ++kg) {
            float a0 = row[kg].x, a1 = row[kg].y, a2 = row[kg].z, a3 = row[kg].w;
            const float* w0 = W_gate + (size_t)(kg * 4 + 0) * H + cc * 8;
            const float* w1 = W_gate + (size_t)(kg * 4 + 1) * H + cc * 8;
            const float* w2 = W_gate + (size_t)(kg * 4 + 2) * H + cc * 8;
            const float* w3 = W_gate + (size_t)(kg * 4 + 3) * H + cc * 8;
#pragma unroll
            for (int c = 0; c < 8; ++c) acc[c] = fmaf(a0, w0[c], acc[c]);
#pragma unroll
            for (int c = 0; c < 8; ++c) acc[c] = fmaf(a1, w1[c], acc[c]);
#pragma unroll
            for (int c = 0; c < 8; ++c) acc[c] = fmaf(a2, w2[c], acc[c]);
#pragma unroll
            for (int c = 0; c < 8; ++c) acc[c] = fmaf(a3, w3[c], acc[c]);
        }

        // epilogue: sigmoid gate, blend, store these 8 cols (2 float4)
#pragma unroll
        for (int q = 0; q < 2; ++q) {
            float4 vf = row[cc * 2 + q];  // static index
            float va[4] = {vf.x, vf.y, vf.z, vf.w};
            float oa[4];
#pragma unroll
            for (int e = 0; e < 4; ++e) {
                int h = cc * 8 + q * 4 + e;
                float x = acc[q * 4 + e];
                float g = 1.0f / (1.0f + __expf(-x));
                float lf = fmaf(l, W_llr[h], b_llr[h]);
                oa[e] = g * lf + (1.0f - g) * va[e];
            }
            float4 o = {oa[0], oa[1], oa[2], oa[3]};
            orow[cc * 2 + q] = o;
        }
    }
}

extern "C" void kernel_launch(void* const* d_in, const int* in_sizes, int n_in,
                              void* d_out, int out_size, void* d_ws, size_t ws_size,
                              hipStream_t stream) {
    const float* nf     = (const float*)d_in[0];  // node_features [N*H]
    const float* llr    = (const float*)d_in[1];  // original_llr [V]
    const float* W_llr  = (const float*)d_in[2];  // [H]
    const float* b_llr  = (const float*)d_in[3];  // [H]
    const float* W_gate = (const float*)d_in[4];  // [2H*H]
    const float* b_gate = (const float*)d_in[5];  // [H]
    // d_in[6] = var_node_mask (unused by the reference computation)
    float* out = (float*)d_out;
    float* uc  = (float*)d_ws;  // 256 floats

    precompute_uc_kernel<<<1, 128, 0, stream>>>(W_llr, b_llr, W_gate, b_gate, uc);

    // 2344 compute blocks (256 rows each) + 586 copy blocks, interleaved:
    // blocks with b%5==4 take the copy role. Total = 2930.
    int totalBlocks = 2930;
    fused_residual_llr_kernel<<<totalBlocks, 256, 0, stream>>>(
        nf, llr, W_llr, b_llr, W_gate, uc, out);
}

// Round 3
// 282.274 us; speedup vs baseline: 4.2366x; 4.2366x over previous
//
#include <hip/hip_runtime.h>
#include <hip/hip_bf16.h>

// N=1e6 nodes, V=6e5 var nodes, H=128.
constexpr int H = 128;
constexpr int V = 600000;
constexpr int NTOT = 1000000;

typedef short bf16x8 __attribute__((ext_vector_type(8)));   // 8 bf16 = 4 VGPR
typedef float f32x4 __attribute__((ext_vector_type(4)));

__device__ inline short f2bf(float f) {  // round-to-nearest-even bf16
    unsigned u = __float_as_uint(f);
    u += 0x7FFF + ((u >> 16) & 1);
    return (short)(u >> 16);
}

// uc[h]=u, uc[128+h]=c :  logits[i][h] = vf_i . W1[:,h] + llr_i*u[h] + c[h]
__global__ void precompute_uc_kernel(const float* __restrict__ W_llr,
                                     const float* __restrict__ b_llr,
                                     const float* __restrict__ W_gate,
                                     const float* __restrict__ b_gate,
                                     float* __restrict__ uc) {
    int h = threadIdx.x;  // 128 threads
    float u = 0.0f, c = 0.0f;
    for (int k = 0; k < H; ++k) {
        float w2 = W_gate[(size_t)(H + k) * H + h];
        u += W_llr[k] * w2;
        c += b_llr[k] * w2;
    }
    uc[h] = u;
    uc[H + h] = c + b_gate[h];
    uc[2 * H + h] = W_llr[h];
    uc[3 * H + h] = b_llr[h];
}

// LDS byte layout:
//   [0, 34816)     Wt: 128 n-rows x 272 B (bf16 k-major, pad +16B -> 2-way banks)
//                  after B-frag preload this region is reused as the A-tile
//                  (64 rows x 272 B = 17408 B).
//   [34816, 36864) vec: u[128], c[128], W_llr[128], b_llr[128] (fp32)
//   [36864, 37120) llr tile (64 fp32)
#define LDS_BYTES 37120
#define VEC_OFF 34816
#define LLR_OFF 36864
#define ROWB 272  // 16-aligned; 272/4 mod 32 = 4 -> 2-way bank aliasing (free)

__global__ __launch_bounds__(256, 3) void fused_residual_llr_kernel(
    const float* __restrict__ nf,      // [N][H]
    const float* __restrict__ llr,     // [V]
    const float* __restrict__ W_gate,  // [2H][H]
    const float* __restrict__ uc,      // [4H]: u, c, W_llr, b_llr
    float* __restrict__ out) {         // [N][H]
    int b = blockIdx.x;
    int tid = threadIdx.x;

    if ((b & 3) == 3) {
        // ---- copy role: rows V..N, coalesced float4, exact partition ----
        size_t base = (size_t)V * H;
        const float4* src = reinterpret_cast<const float4*>(nf + base);
        float4* dst = reinterpret_cast<float4*>(out + base);
        size_t n4 = ((size_t)(NTOT - V) * H) / 4;        // 12.8M
        size_t i = (size_t)(b >> 2) * 256 + tid;
        size_t stride = 625u * 256u;                     // 625 copy blocks
        for (; i < n4; i += stride) dst[i] = src[i];
        return;
    }
    int cb = (b >> 2) * 3 + (b & 3);  // compute-block index 0..1874

    __shared__ __align__(16) char lds[LDS_BYTES];
    float* vecf = reinterpret_cast<float*>(lds + VEC_OFF);  // u,c,Wl,bl
    float* llrl = reinterpret_cast<float*>(lds + LLR_OFF);

    // ---- one-time: stage W1^T (bf16) + u/c/Wl/bl vectors ----
#pragma unroll 4
    for (int j = 0; j < 16; ++j) {  // 4096 float4 of W1
        int idx = tid + 256 * j;
        int k = idx >> 5, c4 = idx & 31;
        float4 wv = reinterpret_cast<const float4*>(W_gate)[(size_t)k * 32 + c4];
        float wa[4] = {wv.x, wv.y, wv.z, wv.w};
#pragma unroll
        for (int e = 0; e < 4; ++e) {
            int n = c4 * 4 + e;
            *reinterpret_cast<short*>(lds + n * ROWB + k * 2) = f2bf(wa[e]);
        }
    }
    if (tid < 128) {
        vecf[tid]       = uc[tid];        // u
        vecf[128 + tid] = uc[128 + tid];  // c
        vecf[256 + tid] = uc[256 + tid];  // W_llr
        vecf[384 + tid] = uc[384 + tid];  // b_llr
    }
    __syncthreads();

    // ---- preload B fragments (held in VGPRs across all tiles) ----
    int lane = tid & 63;
    int w = tid >> 6;          // wave 0..3
    int wr = w >> 1;           // row half 0..1  (32 rows)
    int wc = w & 1;            // col half 0..1  (64 cols)
    int l15 = lane & 15;
    int l4 = lane >> 4;

    bf16x8 Bf[4][4];  // [kk][nf]
#pragma unroll
    for (int kk = 0; kk < 4; ++kk)
#pragma unroll
        for (int nfr = 0; nfr < 4; ++nfr) {
            int n = wc * 64 + nfr * 16 + l15;
            Bf[kk][nfr] = *reinterpret_cast<const bf16x8*>(
                lds + n * ROWB + kk * 64 + l4 * 16);
        }

    const float* u_l = vecf;
    const float* c_l = vecf + 128;

    // ---- tile loop: 5 tiles of 64 rows per block ----
#pragma unroll 1
    for (int t = 0; t < 5; ++t) {
        int rowBase = (cb * 5 + t) * 64;
        __syncthreads();  // prior LDS reads (incl. B preload) done before overwrite

        // stage A-tile: 64 rows x 128 f32 -> bf16 LDS, coalesced
#pragma unroll
        for (int j = 0; j < 8; ++j) {
            int idx = tid + 256 * j;
            int r = idx >> 5, c4 = idx & 31;
            float4 a = reinterpret_cast<const float4*>(nf)[(size_t)(rowBase + r) * 32 + c4];
            short4 p;
            p.x = f2bf(a.x); p.y = f2bf(a.y); p.z = f2bf(a.z); p.w = f2bf(a.w);
            *reinterpret_cast<short4*>(lds + r * ROWB + c4 * 8) = p;
        }
        if (tid < 64) llrl[tid] = llr[rowBase + tid];
        __syncthreads();

        // MFMA: wave computes 32 rows x 64 cols
        f32x4 acc[2][4];
#pragma unroll
        for (int mf = 0; mf < 2; ++mf)
#pragma unroll
            for (int nfr = 0; nfr < 4; ++nfr)
                acc[mf][nfr] = (f32x4){0.f, 0.f, 0.f, 0.f};

#pragma unroll
        for (int kk = 0; kk < 4; ++kk) {
            bf16x8 a0 = *reinterpret_cast<const bf16x8*>(
                lds + (wr * 32 + 0 + l15) * ROWB + kk * 64 + l4 * 16);
            bf16x8 a1 = *reinterpret_cast<const bf16x8*>(
                lds + (wr * 32 + 16 + l15) * ROWB + kk * 64 + l4 * 16);
#pragma unroll
            for (int nfr = 0; nfr < 4; ++nfr) {
                acc[0][nfr] = __builtin_amdgcn_mfma_f32_16x16x32_bf16(
                    a0, Bf[kk][nfr], acc[0][nfr], 0, 0, 0);
                acc[1][nfr] = __builtin_amdgcn_mfma_f32_16x16x32_bf16(
                    a1, Bf[kk][nfr], acc[1][nfr], 0, 0, 0);
            }
        }

        // epilogue: + llr*u + c, sigmoid, blend with vf (bf16 from LDS), store
#pragma unroll
        for (int mf = 0; mf < 2; ++mf) {
#pragma unroll
            for (int reg = 0; reg < 4; ++reg) {
                int rloc = wr * 32 + mf * 16 + l4 * 4 + reg;
                float l_r = llrl[rloc];
#pragma unroll
                for (int nfr = 0; nfr < 4; ++nfr) {
                    int col = wc * 64 + nfr * 16 + l15;
                    float x = acc[mf][nfr][reg] + fmaf(l_r, u_l[col], c_l[col]);
                    float g = 1.0f / (1.0f + __expf(-x));
                    unsigned short vs = *reinterpret_cast<const unsigned short*>(
                        lds + rloc * ROWB + col * 2);
                    float vf = __uint_as_float((unsigned)vs << 16);
                    float lf = fmaf(l_r, vecf[256 + col], vecf[384 + col]);
                    float o = fmaf(g, lf - vf, vf);
                    out[(size_t)(rowBase + rloc) * H + col] = o;
                }
            }
        }
    }
}

extern "C" void kernel_launch(void* const* d_in, const int* in_sizes, int n_in,
                              void* d_out, int out_size, void* d_ws, size_t ws_size,
                              hipStream_t stream) {
    const float* nf     = (const float*)d_in[0];
    const float* llr    = (const float*)d_in[1];
    const float* W_llr  = (const float*)d_in[2];
    const float* b_llr  = (const float*)d_in[3];
    const float* W_gate = (const float*)d_in[4];
    const float* b_gate = (const float*)d_in[5];
    float* out = (float*)d_out;
    float* uc  = (float*)d_ws;  // 512 floats: u, c, W_llr, b_llr

    precompute_uc_kernel<<<1, 128, 0, stream>>>(W_llr, b_llr, W_gate, b_gate, uc);

    // 1875 compute blocks (5 tiles of 64 rows = 600000 rows exactly)
    // + 625 copy blocks, interleaved b&3==3. Total 2500.
    fused_residual_llr_kernel<<<2500, 256, 0, stream>>>(nf, llr, W_gate, uc, out);
}